// Round 1
// baseline (809.308 us; speedup 1.0000x reference)
//
#include <hip/hip_runtime.h>

#define S_ 1024
#define M_ 1024
#define T_ 2048
#define B_ 4
#define H_ 16
#define DM_ 1024
#define DH_ 64

typedef __attribute__((ext_vector_type(8))) short s16x8;
typedef __attribute__((ext_vector_type(16))) float f32x16;

__device__ __forceinline__ unsigned short f2b(float x){
  unsigned int u = __float_as_uint(x);
  u = (u + 0x7fffu + ((u>>16)&1u)) >> 16;
  return (unsigned short)u;
}
__device__ __forceinline__ float b2f(unsigned short h){
  return __uint_as_float(((unsigned int)h)<<16);
}
__device__ __forceinline__ uint4 pack8(const float* v){
  uint4 o;
  o.x = (unsigned)f2b(v[0]) | ((unsigned)f2b(v[1])<<16);
  o.y = (unsigned)f2b(v[2]) | ((unsigned)f2b(v[3])<<16);
  o.z = (unsigned)f2b(v[4]) | ((unsigned)f2b(v[5])<<16);
  o.w = (unsigned)f2b(v[6]) | ((unsigned)f2b(v[7])<<16);
  return o;
}

// ---------------- cast kernels ----------------
// dst[i*8..] = bf16(concat(a,b)[i*8..]); a has na8*8 elements.
__global__ __launch_bounds__(256) void cast_cat(const float* __restrict__ a,
    const float* __restrict__ b, unsigned short* __restrict__ dst, int n8, int na8)
{
  int i = blockIdx.x*256 + threadIdx.x;
  if (i >= n8) return;
  const float* src = (i < na8) ? (a + (size_t)i*8) : (b + ((size_t)(i-na8))*8);
  float4 x0 = *(const float4*)src;
  float4 x1 = *(const float4*)(src+4);
  float f[8] = {x0.x,x0.y,x0.z,x0.w,x1.x,x1.y,x1.z,x1.w};
  *(uint4*)&dst[(size_t)i*8] = pack8(f);
}

// ---------------- GEMM: C[M][N] = A[M][K] @ B[N][K]^T  (bf16 in, NT) ----------------
// mode 0: write bf16 C.  mode 1: write fp32 C + res (residual), res same layout.
__global__ __launch_bounds__(256) void gemm_nt(const unsigned short* __restrict__ A,
    const unsigned short* __restrict__ Bw, void* __restrict__ Cout,
    const float* __restrict__ res, int Ntot, int K, int mode)
{
  __shared__ __align__(16) unsigned short a_s[128*72];
  __shared__ __align__(16) unsigned short b_s[128*72];
  const int tid = threadIdx.x;
  const int lane = tid & 63, wave = tid >> 6;
  const int wr = wave >> 1, wc = wave & 1;
  const long m0 = (long)blockIdx.y * 128, n0 = (long)blockIdx.x * 128;
  f32x16 acc[2][2];
  for (int qa=0;qa<2;qa++) for(int qb=0;qb<2;qb++) for (int e=0;e<16;e++) acc[qa][qb][e]=0.f;
  for (int k0 = 0; k0 < K; k0 += 64) {
    for (int c = 0; c < 4; c++) {
      int ch = c*256 + tid;
      int row = ch >> 3, off = (ch & 7)*8;
      *(uint4*)&a_s[row*72 + off] = *(const uint4*)&A[(size_t)(m0+row)*K + k0 + off];
      *(uint4*)&b_s[row*72 + off] = *(const uint4*)&Bw[(size_t)(n0+row)*K + k0 + off];
    }
    __syncthreads();
    for (int ks = 0; ks < 4; ks++) {
      const int koff = ks*16 + (lane>>5)*8;
      s16x8 af[2], bf[2];
      for (int q = 0; q < 2; q++) {
        af[q] = *(const s16x8*)&a_s[(wr*64 + q*32 + (lane&31))*72 + koff];
        bf[q] = *(const s16x8*)&b_s[(wc*64 + q*32 + (lane&31))*72 + koff];
      }
      for (int qr=0;qr<2;qr++)
        for (int qc2=0;qc2<2;qc2++)
          acc[qr][qc2] = __builtin_amdgcn_mfma_f32_32x32x16_bf16(af[qr], bf[qc2], acc[qr][qc2], 0,0,0);
    }
    __syncthreads();
  }
  for (int qr=0;qr<2;qr++)
    for (int qc2=0;qc2<2;qc2++)
      for (int e=0;e<16;e++){
        long row = m0 + wr*64 + qr*32 + (e&3) + 8*(e>>2) + 4*(lane>>5);
        long col = n0 + wc*64 + qc2*32 + (lane&31);
        size_t o = (size_t)row*Ntot + col;
        if (mode == 0) ((unsigned short*)Cout)[o] = f2b(acc[qr][qc2][e]);
        else           ((float*)Cout)[o] = acc[qr][qc2][e] + res[o];
      }
}

// ---------------- scatter: per-head layouts ----------------
__global__ __launch_bounds__(256) void scatter_quv(const unsigned short* __restrict__ qkvo,
   const float* __restrict__ u, const float* __restrict__ v,
   unsigned short* __restrict__ QU, unsigned short* __restrict__ QV)
{
  int gid = blockIdx.x*256 + threadIdx.x;   // B*H*S*8 = 524288
  int d0 = (gid & 7) * 8;
  int i  = (gid >> 3) & (S_-1);
  int bh = gid >> 13;
  int b = bh >> 4, h = bh & 15;
  size_t src = (size_t)((M_+i)*B_ + b)*3072 + h*64 + d0;
  uint4 q8 = *(const uint4*)&qkvo[src];
  float f[8];
  f[0]=b2f(q8.x&0xffff); f[1]=b2f(q8.x>>16); f[2]=b2f(q8.y&0xffff); f[3]=b2f(q8.y>>16);
  f[4]=b2f(q8.z&0xffff); f[5]=b2f(q8.z>>16); f[6]=b2f(q8.w&0xffff); f[7]=b2f(q8.w>>16);
  float fu[8], fv[8];
  for (int e=0;e<8;e++){ fu[e] = f[e] + u[h*64+d0+e]; fv[e] = f[e] + v[h*64+d0+e]; }
  size_t dst = ((size_t)bh*S_ + i)*64 + d0;
  *(uint4*)&QU[dst] = pack8(fu);
  *(uint4*)&QV[dst] = pack8(fv);
}

__global__ __launch_bounds__(256) void scatter_kvr(const unsigned short* __restrict__ qkvo,
   const unsigned short* __restrict__ relo,
   unsigned short* __restrict__ Kh, unsigned short* __restrict__ Vh, unsigned short* __restrict__ Rh)
{
  int gid = blockIdx.x*256 + threadIdx.x;   // B*H*T*8 = 1048576
  int d0 = (gid & 7) * 8;
  int t  = (gid >> 3) & (T_-1);
  int bh = gid >> 14;
  int b = bh >> 4, h = bh & 15;
  size_t row = (size_t)(t*B_ + b);
  size_t dst = ((size_t)bh*T_ + t)*64 + d0;
  *(uint4*)&Kh[dst] = *(const uint4*)&qkvo[row*3072 + 1024 + h*64 + d0];
  *(uint4*)&Vh[dst] = *(const uint4*)&qkvo[row*3072 + 2048 + h*64 + d0];
  *(uint4*)&Rh[dst] = *(const uint4*)&relo[row*1024 + h*64 + d0];
}

// ---------------- fused rel-attention (flash-style, online softmax) ----------------
// grid: (bh=64, itile=32), block 256. Per block: 32 query rows, loop j-tiles of 64.
__global__ __launch_bounds__(256) void flash_attn(
    const unsigned short* __restrict__ QU, const unsigned short* __restrict__ QV,
    const unsigned short* __restrict__ Kh, const unsigned short* __restrict__ Vh,
    const unsigned short* __restrict__ Rh, unsigned short* __restrict__ AV)
{
  __shared__ __align__(16) unsigned short qu_s[32*72];
  __shared__ __align__(16) unsigned short qv_s[33*72];   // rows i0..i0+32 (band2 uses +1)
  __shared__ __align__(16) unsigned short k_s[64*72];    // unioned with float sc[32*68]
  __shared__ __align__(16) unsigned short v_s[64*72];
  __shared__ __align__(16) unsigned short r1_s[96*72];
  __shared__ __align__(16) unsigned short b1_s[32*96];
  __shared__ __align__(16) unsigned short b2_s[32*96];
  __shared__ float m_s[32], l_s[32], al_s[32];

  const int tid = threadIdx.x, lane = tid&63, wave = tid>>6;
  const int bh = blockIdx.x;
  const int b = bh >> 4, h = bh & 15;
  const int i0 = blockIdx.y*32;
  const int jh = wave >> 1, qc = wave & 1;
  float* scp = (float*)k_s;

  const unsigned short* QUb = QU + (size_t)bh*S_*DH_;
  const unsigned short* QVb = QV + (size_t)bh*S_*DH_;
  const unsigned short* Kb  = Kh + (size_t)bh*T_*DH_;
  const unsigned short* Vb  = Vh + (size_t)bh*T_*DH_;
  const unsigned short* Rb  = Rh + (size_t)bh*T_*DH_;

  {
    int row = tid>>3, off = (tid&7)*8;
    *(uint4*)&qu_s[row*72+off] = *(const uint4*)&QUb[(size_t)(i0+row)*DH_ + off];
    *(uint4*)&qv_s[row*72+off] = *(const uint4*)&QVb[(size_t)(i0+row)*DH_ + off];
    if (tid < 8) {
      int rr = i0 + 32; if (rr > S_-1) rr = S_-1;
      *(uint4*)&qv_s[32*72 + tid*8] = *(const uint4*)&QVb[(size_t)rr*DH_ + tid*8];
    }
    if (tid < 32) { m_s[tid] = -1e30f; l_s[tid] = 0.f; }
  }
  f32x16 acc_o;
  for (int e=0;e<16;e++) acc_o[e] = 0.f;

  for (int j0 = 0; j0 < T_; j0 += 64) {
    const int jlo = j0 + S_ - 32 - i0;           // band1 r-row base (>=0 always)
    const int tlo = j0 - i0 - M_ - 33;           // band2 r-row base (may be <0)
    const bool wrap = (j0 + 63 + (S_-1) - i0) >= T_ + 1;

    // P0: stage K, V, band1 R rows
    for (int c2 = 0; c2 < 2; c2++) {
      int ch = c2*256 + tid; int row = ch>>3, off = (ch&7)*8;
      *(uint4*)&k_s[row*72+off] = *(const uint4*)&Kb[(size_t)(j0+row)*DH_ + off];
      *(uint4*)&v_s[row*72+off] = *(const uint4*)&Vb[(size_t)(j0+row)*DH_ + off];
    }
    for (int c2 = 0; c2 < 3; c2++) {
      int ch = c2*256 + tid; int row = ch>>3, off = (ch&7)*8;
      int jr = jlo + row; if (jr > T_-1) jr = T_-1;
      *(uint4*)&r1_s[row*72+off] = *(const uint4*)&Rb[(size_t)jr*DH_ + off];
    }
    __syncthreads();

    // P1: MFMAs.  waves 0,1: AC quads (kept in regs). waves 2,3: band1 qb 0,1.
    //     second job: wave0 -> band1 qb2; waves1-3 -> band2 qb0-2 (if wrap).
    f32x16 acc_ac;
    if (wave < 2) {
      for (int e=0;e<16;e++) acc_ac[e]=0.f;
      for (int ks=0; ks<4; ks++) {
        int koff = ks*16 + (lane>>5)*8;
        s16x8 a  = *(const s16x8*)&qu_s[(lane&31)*72 + koff];
        s16x8 bq = *(const s16x8*)&k_s[(wave*32 + (lane&31))*72 + koff];
        acc_ac = __builtin_amdgcn_mfma_f32_32x32x16_bf16(a, bq, acc_ac, 0,0,0);
      }
    } else {
      int qb = wave - 2;
      f32x16 bacc; for (int e=0;e<16;e++) bacc[e]=0.f;
      for (int ks=0; ks<4; ks++) {
        int koff = ks*16 + (lane>>5)*8;
        s16x8 a  = *(const s16x8*)&qv_s[(lane&31)*72 + koff];
        s16x8 bb = *(const s16x8*)&r1_s[(qb*32 + (lane&31))*72 + koff];
        bacc = __builtin_amdgcn_mfma_f32_32x32x16_bf16(a, bb, bacc, 0,0,0);
      }
      for (int e=0;e<16;e++){
        int r = (e&3) + 8*(e>>2) + 4*(lane>>5);
        b1_s[r*96 + qb*32 + (lane&31)] = f2b(bacc[e]);
      }
    }
    if (wave == 0) {
      f32x16 bacc; for (int e=0;e<16;e++) bacc[e]=0.f;
      for (int ks=0; ks<4; ks++) {
        int koff = ks*16 + (lane>>5)*8;
        s16x8 a  = *(const s16x8*)&qv_s[(lane&31)*72 + koff];
        s16x8 bb = *(const s16x8*)&r1_s[(64 + (lane&31))*72 + koff];
        bacc = __builtin_amdgcn_mfma_f32_32x32x16_bf16(a, bb, bacc, 0,0,0);
      }
      for (int e=0;e<16;e++){
        int r = (e&3) + 8*(e>>2) + 4*(lane>>5);
        b1_s[r*96 + 64 + (lane&31)] = f2b(bacc[e]);
      }
    } else if (wrap) {
      int qb = wave - 1;
      f32x16 bacc; for (int e=0;e<16;e++) bacc[e]=0.f;
      for (int ks=0; ks<4; ks++) {
        int koff = ks*16 + (lane>>5)*8;
        s16x8 a = *(const s16x8*)&qv_s[(1 + (lane&31))*72 + koff];
        int tr = tlo + qb*32 + (lane&31);
        tr = tr < 0 ? 0 : (tr > T_-1 ? T_-1 : tr);
        s16x8 bb = *(const s16x8*)&Rb[(size_t)tr*DH_ + koff];
        bacc = __builtin_amdgcn_mfma_f32_32x32x16_bf16(a, bb, bacc, 0,0,0);
      }
      for (int e=0;e<16;e++){
        int r = (e&3) + 8*(e>>2) + 4*(lane>>5);
        b2_s[r*96 + qb*32 + (lane&31)] = f2b(bacc[e]);
      }
    }
    __syncthreads();

    // P2: assemble scores (waves 0,1) -> scp (overwrites k_s region)
    if (wave < 2) {
      for (int e=0;e<16;e++){
        int r = (e&3) + 8*(e>>2) + 4*(lane>>5);
        int c = wave*32 + (lane&31);
        int jj = j0 + c + (S_-1) - i0 - r;
        int idx = c - r + 31;
        float bd;
        if (jj < T_)       bd = b2f(b1_s[r*96+idx]);
        else if (jj == T_) bd = 0.f;
        else               bd = b2f(b2_s[r*96+idx]);
        scp[r*68 + c] = (acc_ac[e] + bd) * 0.125f;
      }
    }
    __syncthreads();

    // P3: online softmax; wave w owns rows 8w..8w+7; write P packed bf16 in place
    {
      int r = 8*wave + (lane>>3);
      int cb = (lane&7)*8;
      float4 t0 = *(const float4*)&scp[r*68 + cb];
      float4 t1 = *(const float4*)&scp[r*68 + cb + 4];
      float vv[8] = {t0.x,t0.y,t0.z,t0.w,t1.x,t1.y,t1.z,t1.w};
      float mx = vv[0];
      for (int e=1;e<8;e++) mx = fmaxf(mx, vv[e]);
      mx = fmaxf(mx, __shfl_xor(mx, 1, 64));
      mx = fmaxf(mx, __shfl_xor(mx, 2, 64));
      mx = fmaxf(mx, __shfl_xor(mx, 4, 64));
      float mold = m_s[r];
      float mnew = fmaxf(mold, mx);
      float p[8]; float s = 0.f;
      for (int e=0;e<8;e++){ p[e] = __expf(vv[e]-mnew); s += p[e]; }
      s += __shfl_xor(s, 1, 64);
      s += __shfl_xor(s, 2, 64);
      s += __shfl_xor(s, 4, 64);
      float alpha = __expf(mold - mnew);
      if ((lane&7)==0) { l_s[r] = l_s[r]*alpha + s; m_s[r] = mnew; al_s[r] = alpha; }
      uint4 pk = pack8(p);
      *(uint4*)((char*)scp + (size_t)r*272 + (size_t)(lane&7)*16) = pk;
    }
    __syncthreads();

    // P4: rescale O, PV mfma (wave: j-half jh, dd-half qc)
    for (int e=0;e<16;e++){
      int rr = (e&3) + 8*(e>>2) + 4*(lane>>5);
      acc_o[e] *= al_s[rr];
    }
    for (int ks=0; ks<2; ks++){
      int kf = jh*32 + ks*16 + (lane>>5)*8;
      s16x8 a = *(const s16x8*)((const char*)scp + (size_t)(lane&31)*272 + (size_t)kf*2);
      s16x8 bv;
      for (int e=0;e<8;e++) bv[e] = (short)v_s[(kf+e)*72 + qc*32 + (lane&31)];
      acc_o = __builtin_amdgcn_mfma_f32_32x32x16_bf16(a, bv, acc_o, 0,0,0);
    }
    __syncthreads();
  }

  // epilogue: combine j-halves, divide by l, write bf16
  if (jh == 0) {
    for (int e=0;e<16;e++){
      int r = (e&3) + 8*(e>>2) + 4*(lane>>5);
      scp[r*68 + qc*32 + (lane&31)] = acc_o[e];
    }
  }
  __syncthreads();
  if (jh == 1) {
    for (int e=0;e<16;e++){
      int r = (e&3) + 8*(e>>2) + 4*(lane>>5);
      scp[r*68 + qc*32 + (lane&31)] += acc_o[e];
    }
  }
  __syncthreads();
  {
    int r = tid>>3, d0 = (tid&7)*8;
    float inv = 1.f / l_s[r];
    float4 t0 = *(const float4*)&scp[r*68 + d0];
    float4 t1 = *(const float4*)&scp[r*68 + d0 + 4];
    float vals[8] = {t0.x*inv,t0.y*inv,t0.z*inv,t0.w*inv,t1.x*inv,t1.y*inv,t1.z*inv,t1.w*inv};
    uint4 pk = pack8(vals);
    *(uint4*)&AV[ ((size_t)((i0+r)*B_ + b))*(H_*DH_) + h*DH_ + d0 ] = pk;
  }
}

// ---------------- LayerNorm ----------------
__global__ __launch_bounds__(256) void ln_kernel(const float* __restrict__ y,
    const float* __restrict__ g, const float* __restrict__ be, float* __restrict__ o)
{
  __shared__ float red[8];
  int row = blockIdx.x, tid = threadIdx.x;
  const float* yr = y + (size_t)row*DM_;
  float v[4];
  for (int e=0;e<4;e++) v[e] = yr[tid + 256*e];
  float s = v[0]+v[1]+v[2]+v[3];
  for (int off=32; off>0; off>>=1) s += __shfl_down(s, off, 64);
  if ((tid&63)==0) red[tid>>6] = s;
  __syncthreads();
  if (tid==0) red[4] = red[0]+red[1]+red[2]+red[3];
  __syncthreads();
  float mu = red[4] * (1.f/DM_);
  __syncthreads();
  float q = 0.f;
  for (int e=0;e<4;e++){ float d = v[e]-mu; q += d*d; }
  for (int off=32; off>0; off>>=1) q += __shfl_down(q, off, 64);
  if ((tid&63)==0) red[tid>>6] = q;
  __syncthreads();
  if (tid==0) red[4] = red[0]+red[1]+red[2]+red[3];
  __syncthreads();
  float rstd = rsqrtf(red[4]*(1.f/DM_) + 1e-5f);
  for (int e=0;e<4;e++){
    int c = tid + 256*e;
    o[(size_t)row*DM_ + c] = g[c]*(v[e]-mu)*rstd + be[c];
  }
}

// ---------------- launch ----------------
extern "C" void kernel_launch(void* const* d_in, const int* in_sizes, int n_in,
                              void* d_out, int out_size, void* d_ws, size_t ws_size,
                              hipStream_t stream)
{
  const float* x    = (const float*)d_in[0];
  const float* mem  = (const float*)d_in[1];
  const float* pos  = (const float*)d_in[2];
  const float* pbu  = (const float*)d_in[3];
  const float* pbv  = (const float*)d_in[4];
  const float* wqkv = (const float*)d_in[5];
  const float* wrel = (const float*)d_in[6];
  const float* wo   = (const float*)d_in[7];
  const float* gam  = (const float*)d_in[8];
  const float* bet  = (const float*)d_in[9];
  float* out = (float*)d_out;

  char* w = (char*)d_ws;
  unsigned short* c16   = (unsigned short*)(w + 0);          // 16,777,216 B
  unsigned short* pos16 = (unsigned short*)(w + 16777216);   // 16,777,216
  unsigned short* wq16  = (unsigned short*)(w + 33554432);   // 6,291,456
  unsigned short* wr16  = (unsigned short*)(w + 39845888);   // 2,097,152
  unsigned short* wo16  = (unsigned short*)(w + 41943040);   // 2,097,152
  unsigned short* qkvo  = (unsigned short*)(w + 44040192);   // 50,331,648
  unsigned short* relo  = (unsigned short*)(w + 94371840);   // 16,777,216
  unsigned short* QUb   = (unsigned short*)(w + 111149056);  // 8,388,608
  unsigned short* QVb   = (unsigned short*)(w + 119537664);  // 8,388,608
  unsigned short* Kb    = (unsigned short*)(w + 127926272);  // 16,777,216
  unsigned short* Vb    = (unsigned short*)(w + 144703488);  // 16,777,216
  unsigned short* Rb    = (unsigned short*)(w + 161480704);  // 16,777,216
  unsigned short* av16  = (unsigned short*)(w + 178257920);  // 8,388,608
  float*          yf    = (float*)(w + 186646528);           // 16,777,216  (total ~203 MB)

  // casts to bf16
  cast_cat<<<4096, 256, 0, stream>>>(mem, x, c16, 1048576, 524288);      // c = [memory; x]
  cast_cat<<<4096, 256, 0, stream>>>(pos, pos, pos16, 1048576, 1048576);
  cast_cat<<<1536, 256, 0, stream>>>(wqkv, wqkv, wq16, 393216, 393216);
  cast_cat<<< 512, 256, 0, stream>>>(wrel, wrel, wr16, 131072, 131072);
  cast_cat<<< 512, 256, 0, stream>>>(wo,   wo,   wo16, 131072, 131072);

  // projections
  gemm_nt<<<dim3(24,64), 256, 0, stream>>>(c16,   wq16, (void*)qkvo, nullptr, 3072, 1024, 0);
  gemm_nt<<<dim3(8,64),  256, 0, stream>>>(pos16, wr16, (void*)relo, nullptr, 1024, 1024, 0);

  // head scatter (+u/+v bias into QU/QV)
  scatter_quv<<<2048, 256, 0, stream>>>(qkvo, pbu, pbv, QUb, QVb);
  scatter_kvr<<<4096, 256, 0, stream>>>(qkvo, relo, Kb, Vb, Rb);

  // fused rel-shift attention
  flash_attn<<<dim3(64,32), 256, 0, stream>>>(QUb, QVb, Kb, Vb, Rb, av16);

  // output projection + residual, then LN
  gemm_nt<<<dim3(8,32), 256, 0, stream>>>(av16, wo16, (void*)yf, x, 1024, 1024, 1);
  ln_kernel<<<4096, 256, 0, stream>>>(yf, gam, bet, out);
}

// Round 3
// 551.659 us; speedup vs baseline: 1.4670x; 1.4670x over previous
//
#include <hip/hip_runtime.h>

#define S_ 1024
#define M_ 1024
#define T_ 2048
#define B_ 4
#define H_ 16
#define DM_ 1024
#define DH_ 64

typedef __attribute__((ext_vector_type(8))) short s16x8;
typedef __attribute__((ext_vector_type(16))) float f32x16;

__device__ __forceinline__ unsigned short f2b(float x){
  unsigned int u = __float_as_uint(x);
  u = (u + 0x7fffu + ((u>>16)&1u)) >> 16;
  return (unsigned short)u;
}
__device__ __forceinline__ float b2f(unsigned short h){
  return __uint_as_float(((unsigned int)h)<<16);
}
__device__ __forceinline__ uint4 pack8(const float* v){
  uint4 o;
  o.x = (unsigned)f2b(v[0]) | ((unsigned)f2b(v[1])<<16);
  o.y = (unsigned)f2b(v[2]) | ((unsigned)f2b(v[3])<<16);
  o.z = (unsigned)f2b(v[4]) | ((unsigned)f2b(v[5])<<16);
  o.w = (unsigned)f2b(v[6]) | ((unsigned)f2b(v[7])<<16);
  return o;
}

// ---------------- cast kernels ----------------
__global__ __launch_bounds__(256) void cast_cat(const float* __restrict__ a,
    const float* __restrict__ b, unsigned short* __restrict__ dst, int n8, int na8)
{
  int i = blockIdx.x*256 + threadIdx.x;
  if (i >= n8) return;
  const float* src = (i < na8) ? (a + (size_t)i*8) : (b + ((size_t)(i-na8))*8);
  float4 x0 = *(const float4*)src;
  float4 x1 = *(const float4*)(src+4);
  float f[8] = {x0.x,x0.y,x0.z,x0.w,x1.x,x1.y,x1.z,x1.w};
  *(uint4*)&dst[(size_t)i*8] = pack8(f);
}

// ---------------- GEMM: C[M][N] = A[M][K] @ B[N][K]^T  (bf16 in, NT) ----------------
__global__ __launch_bounds__(256) void gemm_nt(const unsigned short* __restrict__ A,
    const unsigned short* __restrict__ Bw, void* __restrict__ Cout,
    const float* __restrict__ res, int Ntot, int K, int mode)
{
  __shared__ __align__(16) unsigned short a_s[128*72];
  __shared__ __align__(16) unsigned short b_s[128*72];
  const int tid = threadIdx.x;
  const int lane = tid & 63, wave = tid >> 6;
  const int wr = wave >> 1, wc = wave & 1;
  const long m0 = (long)blockIdx.y * 128, n0 = (long)blockIdx.x * 128;
  f32x16 acc[2][2];
  for (int qa=0;qa<2;qa++) for(int qb=0;qb<2;qb++) for (int e=0;e<16;e++) acc[qa][qb][e]=0.f;
  for (int k0 = 0; k0 < K; k0 += 64) {
    for (int c = 0; c < 4; c++) {
      int ch = c*256 + tid;
      int row = ch >> 3, off = (ch & 7)*8;
      *(uint4*)&a_s[row*72 + off] = *(const uint4*)&A[(size_t)(m0+row)*K + k0 + off];
      *(uint4*)&b_s[row*72 + off] = *(const uint4*)&Bw[(size_t)(n0+row)*K + k0 + off];
    }
    __syncthreads();
    for (int ks = 0; ks < 4; ks++) {
      const int koff = ks*16 + (lane>>5)*8;
      s16x8 af[2], bf[2];
      for (int q = 0; q < 2; q++) {
        af[q] = *(const s16x8*)&a_s[(wr*64 + q*32 + (lane&31))*72 + koff];
        bf[q] = *(const s16x8*)&b_s[(wc*64 + q*32 + (lane&31))*72 + koff];
      }
      for (int qr=0;qr<2;qr++)
        for (int qc2=0;qc2<2;qc2++)
          acc[qr][qc2] = __builtin_amdgcn_mfma_f32_32x32x16_bf16(af[qr], bf[qc2], acc[qr][qc2], 0,0,0);
    }
    __syncthreads();
  }
  for (int qr=0;qr<2;qr++)
    for (int qc2=0;qc2<2;qc2++)
      for (int e=0;e<16;e++){
        long row = m0 + wr*64 + qr*32 + (e&3) + 8*(e>>2) + 4*(lane>>5);
        long col = n0 + wc*64 + qc2*32 + (lane&31);
        size_t o = (size_t)row*Ntot + col;
        if (mode == 0) ((unsigned short*)Cout)[o] = f2b(acc[qr][qc2][e]);
        else           ((float*)Cout)[o] = acc[qr][qc2][e] + res[o];
      }
}

// ---------------- bdr GEMM (chunked): F[bhl][S][T+1] = QV[bh] @ relo_bh^T ----------------
__global__ __launch_bounds__(256) void gemm_bdr(const unsigned short* __restrict__ QV,
    const unsigned short* __restrict__ relo, unsigned short* __restrict__ FBD, int bh_base)
{
  __shared__ __align__(16) unsigned short a_s[128*72];
  __shared__ __align__(16) unsigned short b_s[128*72];
  const int tid = threadIdx.x, lane = tid&63, wave = tid>>6;
  const int wr = wave>>1, wc = wave&1;
  const int bhl = blockIdx.z;
  const int bh = bh_base + bhl, b = bh>>4, h = bh&15;
  const int m0 = blockIdx.y*128, n0 = blockIdx.x*128;
  const unsigned short* Ab = QV + (size_t)bh*S_*DH_;
  const unsigned short* Bb = relo + (size_t)b*1024 + h*64;
  unsigned short* Fb = FBD + (size_t)bhl*S_*(T_+1);
  for (int c=0;c<4;c++){
    int ch = c*256+tid; int row = ch>>3, off=(ch&7)*8;
    *(uint4*)&a_s[row*72+off] = *(const uint4*)&Ab[(size_t)(m0+row)*64+off];
    *(uint4*)&b_s[row*72+off] = *(const uint4*)&Bb[(size_t)(n0+row)*4096+off];
  }
  __syncthreads();
  f32x16 acc[2][2];
  for (int qa=0;qa<2;qa++) for(int qb=0;qb<2;qb++) for (int e=0;e<16;e++) acc[qa][qb][e]=0.f;
  for (int ks = 0; ks < 4; ks++) {
    const int koff = ks*16 + (lane>>5)*8;
    s16x8 af[2], bf[2];
    for (int q = 0; q < 2; q++) {
      af[q] = *(const s16x8*)&a_s[(wr*64 + q*32 + (lane&31))*72 + koff];
      bf[q] = *(const s16x8*)&b_s[(wc*64 + q*32 + (lane&31))*72 + koff];
    }
    for (int qa=0;qa<2;qa++)
      for (int qb=0;qb<2;qb++)
        acc[qa][qb] = __builtin_amdgcn_mfma_f32_32x32x16_bf16(af[qa], bf[qb], acc[qa][qb], 0,0,0);
  }
  for (int qa=0;qa<2;qa++)
    for (int qb=0;qb<2;qb++)
      for (int e=0;e<16;e++){
        int row = m0 + wr*64 + qa*32 + (e&3) + 8*(e>>2) + 4*(lane>>5);
        int col = n0 + wc*64 + qb*32 + (lane&31);
        Fb[(size_t)row*(T_+1) + col] = f2b(acc[qa][qb][e]);
      }
}

// ---------------- scatter: q + biases, per-head layout ----------------
__global__ __launch_bounds__(256) void scatter_quv(const unsigned short* __restrict__ qkvo,
   const float* __restrict__ u, const float* __restrict__ v,
   unsigned short* __restrict__ QU, unsigned short* __restrict__ QV)
{
  int gid = blockIdx.x*256 + threadIdx.x;   // B*H*S*8 = 524288
  int d0 = (gid & 7) * 8;
  int i  = (gid >> 3) & (S_-1);
  int bh = gid >> 13;
  int b = bh >> 4, h = bh & 15;
  size_t src = (size_t)((M_+i)*B_ + b)*3072 + h*64 + d0;
  uint4 q8 = *(const uint4*)&qkvo[src];
  float f[8];
  f[0]=b2f(q8.x&0xffff); f[1]=b2f(q8.x>>16); f[2]=b2f(q8.y&0xffff); f[3]=b2f(q8.y>>16);
  f[4]=b2f(q8.z&0xffff); f[5]=b2f(q8.z>>16); f[6]=b2f(q8.w&0xffff); f[7]=b2f(q8.w>>16);
  float fu[8], fv[8];
  for (int e=0;e<8;e++){ fu[e] = f[e] + u[h*64+d0+e]; fv[e] = f[e] + v[h*64+d0+e]; }
  size_t dst = ((size_t)bh*S_ + i)*64 + d0;
  *(uint4*)&QU[dst] = pack8(fu);
  *(uint4*)&QV[dst] = pack8(fv);
}

// ---------------- fused attention: AC via MFMA + BD from chunked FBD ----------------
// grid (bhl=16, itile=16, z=2), block 256 (4 waves, one 32x32 quad each).
// z halves the j-range; partial O (bf16) and l (fp32) written; combined later.
__global__ __launch_bounds__(256,4) void flash_attn2(
    const unsigned short* __restrict__ QU, const unsigned short* __restrict__ qkvo,
    const unsigned short* __restrict__ FBD, unsigned short* __restrict__ Opart,
    float* __restrict__ lpart, int bh_base)
{
  __shared__ __align__(16) unsigned short qu_s[64*72];
  __shared__ __align__(16) unsigned short k_s[64*72];
  __shared__ __align__(16) unsigned short vT_s[64*64];
  __shared__ __align__(16) unsigned short p_s[64*72];

  const int tid = threadIdx.x, lane = tid&63, wave = tid>>6;
  const int bhl = blockIdx.x;
  const int bh = bh_base + bhl, b = bh>>4, h = bh&15;
  const int i0 = blockIdx.y*64;
  const int z = blockIdx.z;
  const int qr = wave>>1, qc = wave&1;
  const unsigned short* QUb = QU + (size_t)bh*S_*DH_;
  const unsigned short* Kg = qkvo + (size_t)b*3072 + 1024 + h*64;   // + t*12288
  const unsigned short* Vg = qkvo + (size_t)b*3072 + 2048 + h*64;
  const unsigned short* Fb = FBD + (size_t)bhl*S_*(T_+1);

  for (int c=0;c<2;c++){
    int ch = c*256+tid; int row = ch>>3, off=(ch&7)*8;
    *(uint4*)&qu_s[row*72+off] = *(const uint4*)&QUb[(size_t)(i0+row)*64 + off];
  }

  f32x16 acc_o;
  for (int e=0;e<16;e++) acc_o[e]=0.f;
  float lreg = 0.f;

  const int col = qc*32 + (lane&31);
  int rowl[16];
  for (int e=0;e<16;e++) rowl[e] = qr*32 + (e&3) + 8*(e>>2) + 4*(lane>>5);

  const int jbeg = z*(T_/2), jend = jbeg + (T_/2);
  for (int j0 = jbeg; j0 < jend; j0 += 64) {
    for (int c=0;c<2;c++){
      int ch = c*256+tid; int row = ch>>3, off=(ch&7)*8;
      uint4 kk = *(const uint4*)&Kg[(size_t)(j0+row)*12288 + off];
      *(uint4*)&k_s[row*72+off] = kk;
      uint4 vv = *(const uint4*)&Vg[(size_t)(j0+row)*12288 + off];
      unsigned short ve[8] = {
        (unsigned short)(vv.x&0xffff),(unsigned short)(vv.x>>16),
        (unsigned short)(vv.y&0xffff),(unsigned short)(vv.y>>16),
        (unsigned short)(vv.z&0xffff),(unsigned short)(vv.z>>16),
        (unsigned short)(vv.w&0xffff),(unsigned short)(vv.w>>16)};
      for (int e=0;e<8;e++){
        int d = off + e;
        vT_s[d*64 + (row ^ (8*((d>>3)&7)))] = ve[e];
      }
    }
    unsigned short bdu[16];
    const int jj = j0 + col;
    for (int e=0;e<16;e++)
      bdu[e] = Fb[(size_t)(i0+rowl[e])*T_ + jj + (S_-1)];
    __syncthreads();

    f32x16 acc;
    for (int e=0;e<16;e++) acc[e]=0.f;
    for (int ks=0; ks<4; ks++){
      const int koff = ks*16 + (lane>>5)*8;
      s16x8 a  = *(const s16x8*)&qu_s[(qr*32+(lane&31))*72 + koff];
      s16x8 bq = *(const s16x8*)&k_s[(qc*32+(lane&31))*72 + koff];
      acc = __builtin_amdgcn_mfma_f32_32x32x16_bf16(a, bq, acc, 0,0,0);
    }
    for (int e=0;e<16;e++){
      int i = i0 + rowl[e];
      float bdv = (jj - i == M_+1) ? 0.f : b2f(bdu[e]);
      float p = __expf((acc[e] + bdv) * 0.125f);
      p_s[rowl[e]*72 + col] = f2b(p);
    }
    __syncthreads();

    {
      int rr = tid>>2, cb = (tid&3)*16;
      uint4 x0 = *(const uint4*)&p_s[rr*72+cb];
      uint4 x1 = *(const uint4*)&p_s[rr*72+cb+8];
      unsigned vs[8] = {x0.x,x0.y,x0.z,x0.w,x1.x,x1.y,x1.z,x1.w};
      float s = 0.f;
      for (int e=0;e<8;e++) s += b2f((unsigned short)(vs[e]&0xffff)) + b2f((unsigned short)(vs[e]>>16));
      s += __shfl_xor(s, 1, 64);
      s += __shfl_xor(s, 2, 64);
      if ((tid&3)==0) lreg += s;
    }
    for (int ks=0; ks<4; ks++){
      const int koff = ks*16 + (lane>>5)*8;
      s16x8 a = *(const s16x8*)&p_s[(qr*32+(lane&31))*72 + koff];
      int dcol = qc*32 + (lane&31);
      s16x8 bv = *(const s16x8*)&vT_s[dcol*64 + (koff ^ (8*((dcol>>3)&7)))];
      acc_o = __builtin_amdgcn_mfma_f32_32x32x16_bf16(a, bv, acc_o, 0,0,0);
    }
    __syncthreads();
  }

  // write partials
  if ((tid&3)==0)
    lpart[(size_t)z*(64*S_) + (size_t)bh*S_ + i0 + (tid>>2)] = lreg;
  for (int e=0;e<16;e++){
    size_t n = ((size_t)(i0+rowl[e])*B_ + b)*(H_*DH_) + h*DH_ + col;
    Opart[(size_t)z*(4096u*1024u) + n] = f2b(acc_o[e]);
  }
}

// ---------------- combine partials: AV = (O0+O1)/(l0+l1) ----------------
__global__ __launch_bounds__(256) void combine_o(const unsigned short* __restrict__ Opart,
    const float* __restrict__ lpart, unsigned short* __restrict__ AV)
{
  int gid = blockIdx.x*256 + threadIdx.x;    // 524288
  size_t n = (size_t)gid*8;
  int h = (int)((n>>6) & 15);
  int b = (int)((n>>10) & 3);
  int i = (int)(n >> 12);
  int bh = b*16 + h;
  float l = lpart[(size_t)bh*S_ + i] + lpart[(size_t)64*S_ + (size_t)bh*S_ + i];
  float inv = 1.f / l;
  uint4 o0 = *(const uint4*)&Opart[n];
  uint4 o1 = *(const uint4*)&Opart[(size_t)4096*1024 + n];
  unsigned a0[4] = {o0.x,o0.y,o0.z,o0.w}, a1[4] = {o1.x,o1.y,o1.z,o1.w};
  float f[8];
  for (int e=0;e<4;e++){
    f[2*e]   = (b2f((unsigned short)(a0[e]&0xffff)) + b2f((unsigned short)(a1[e]&0xffff))) * inv;
    f[2*e+1] = (b2f((unsigned short)(a0[e]>>16))    + b2f((unsigned short)(a1[e]>>16)))    * inv;
  }
  *(uint4*)&AV[n] = pack8(f);
}

// ---------------- LayerNorm ----------------
__global__ __launch_bounds__(256) void ln_kernel(const float* __restrict__ y,
    const float* __restrict__ g, const float* __restrict__ be, float* __restrict__ o)
{
  __shared__ float red[8];
  int row = blockIdx.x, tid = threadIdx.x;
  const float* yr = y + (size_t)row*DM_;
  float v[4];
  for (int e=0;e<4;e++) v[e] = yr[tid + 256*e];
  float s = v[0]+v[1]+v[2]+v[3];
  for (int off=32; off>0; off>>=1) s += __shfl_down(s, off, 64);
  if ((tid&63)==0) red[tid>>6] = s;
  __syncthreads();
  if (tid==0) red[4] = red[0]+red[1]+red[2]+red[3];
  __syncthreads();
  float mu = red[4] * (1.f/DM_);
  __syncthreads();
  float q = 0.f;
  for (int e=0;e<4;e++){ float d = v[e]-mu; q += d*d; }
  for (int off=32; off>0; off>>=1) q += __shfl_down(q, off, 64);
  if ((tid&63)==0) red[tid>>6] = q;
  __syncthreads();
  if (tid==0) red[4] = red[0]+red[1]+red[2]+red[3];
  __syncthreads();
  float rstd = rsqrtf(red[4]*(1.f/DM_) + 1e-5f);
  for (int e=0;e<4;e++){
    int c = tid + 256*e;
    o[(size_t)row*DM_ + c] = g[c]*(v[e]-mu)*rstd + be[c];
  }
}

// ---------------- launch ----------------
extern "C" void kernel_launch(void* const* d_in, const int* in_sizes, int n_in,
                              void* d_out, int out_size, void* d_ws, size_t ws_size,
                              hipStream_t stream)
{
  const float* x    = (const float*)d_in[0];
  const float* mem  = (const float*)d_in[1];
  const float* pos  = (const float*)d_in[2];
  const float* pbu  = (const float*)d_in[3];
  const float* pbv  = (const float*)d_in[4];
  const float* wqkv = (const float*)d_in[5];
  const float* wrel = (const float*)d_in[6];
  const float* wo   = (const float*)d_in[7];
  const float* gam  = (const float*)d_in[8];
  const float* bet  = (const float*)d_in[9];
  float* out = (float*)d_out;

  char* w = (char*)d_ws;
  // FBD chunk region [0, 67,141,632); cast transients overlaid (dead before first bdr)
  unsigned short* FBD   = (unsigned short*)(w + 0);
  unsigned short* c16   = (unsigned short*)(w + 0);
  unsigned short* pos16 = (unsigned short*)(w + 16777216);
  unsigned short* wq16  = (unsigned short*)(w + 33554432);
  unsigned short* wr16  = (unsigned short*)(w + 39845888);
  unsigned short* qkvo  = (unsigned short*)(w + 67141632);   // 50,331,648
  unsigned short* relo  = (unsigned short*)(w + 117473280);  // 16,777,216
  unsigned short* wo16  = (unsigned short*)(w + 134250496);  //  2,097,152
  unsigned short* QUb   = (unsigned short*)(w + 136347648);  //  8,388,608
  unsigned short* QVb   = (unsigned short*)(w + 144736256);  //  8,388,608
  unsigned short* av16  = (unsigned short*)(w + 153124864);  //  8,388,608
  float*          yf    = (float*)(w + 161513472);           // 16,777,216
  unsigned short* Opart = (unsigned short*)(w + 178290688);  // 16,777,216
  float*          lpart = (float*)(w + 195067904);           //    524,288  -> total 195,592,192

  cast_cat<<<4096, 256, 0, stream>>>(mem, x, c16, 1048576, 524288);
  cast_cat<<<4096, 256, 0, stream>>>(pos, pos, pos16, 1048576, 1048576);
  cast_cat<<<1536, 256, 0, stream>>>(wqkv, wqkv, wq16, 393216, 393216);
  cast_cat<<< 512, 256, 0, stream>>>(wrel, wrel, wr16, 131072, 131072);
  cast_cat<<< 512, 256, 0, stream>>>(wo,   wo,   wo16, 131072, 131072);

  gemm_nt<<<dim3(24,64), 256, 0, stream>>>(c16,   wq16, (void*)qkvo, nullptr, 3072, 1024, 0);
  gemm_nt<<<dim3(8,64),  256, 0, stream>>>(pos16, wr16, (void*)relo, nullptr, 1024, 1024, 0);

  scatter_quv<<<2048, 256, 0, stream>>>(qkvo, pbu, pbv, QUb, QVb);

  for (int cchunk = 0; cchunk < 4; cchunk++) {
    int bh_base = cchunk*16;
    gemm_bdr<<<dim3(16,8,16), 256, 0, stream>>>(QVb, relo, FBD, bh_base);
    flash_attn2<<<dim3(16,16,2), 256, 0, stream>>>(QUb, qkvo, FBD, Opart, lpart, bh_base);
  }
  combine_o<<<2048, 256, 0, stream>>>(Opart, lpart, av16);

  gemm_nt<<<dim3(8,32), 256, 0, stream>>>(av16, wo16, (void*)yf, x, 1024, 1024, 1);
  ln_kernel<<<4096, 256, 0, stream>>>(yf, gam, bet, out);
}